// Round 1
// baseline (219.883 us; speedup 1.0000x reference)
//
#include <hip/hip_runtime.h>
#include <hip/hip_bf16.h>

typedef short bf16x8 __attribute__((ext_vector_type(8)));
typedef float f32x4 __attribute__((ext_vector_type(4)));
typedef unsigned short u16;

constexpr int TOKS = 2048;
constexpr int EMB  = 2048;
constexpr int NH   = 16;
constexpr int HS   = 128;
constexpr float RSQ = 0.08838834764831845f; // 1/sqrt(128)

// workspace layout (bytes)
constexpr size_t OFF_SCAL = 0;                       // 4 floats (absmax)
constexpr size_t OFF_QX   = 1024;
constexpr size_t SZ_MAT   = (size_t)TOKS * EMB * 2;  // 8MB bf16
constexpr size_t OFF_QW   = OFF_QX + SZ_MAT;         // 3 mats
constexpr size_t OFF_Q    = OFF_QW + 3 * SZ_MAT;
constexpr size_t OFF_K    = OFF_Q + SZ_MAT;
constexpr size_t OFF_V    = OFF_K + SZ_MAT;
constexpr size_t OFF_VT   = OFF_V + SZ_MAT;
constexpr size_t OFF_DEN  = OFF_VT + SZ_MAT;         // 16MB f32

__device__ __forceinline__ u16 f2b(float f) {
  unsigned u = __float_as_uint(f);
  unsigned r = (u + 0x7fffu + ((u >> 16) & 1u)) >> 16;
  return (u16)r;
}

__device__ __forceinline__ void gload16(const void* g, void* l) {
  __builtin_amdgcn_global_load_lds(
      (const __attribute__((address_space(1))) unsigned int*)g,
      (__attribute__((address_space(3))) unsigned int*)l, 16, 0, 0);
}

__global__ void k_init(int* scal) {
  if (threadIdx.x < 4) scal[threadIdx.x] = 0;
}

__global__ void k_absmax(const float* __restrict__ x, const float* __restrict__ w1,
                         const float* __restrict__ w2, const float* __restrict__ w3,
                         int* scal) {
  const float* src = (blockIdx.y == 0) ? x : (blockIdx.y == 1) ? w1 : (blockIdx.y == 2) ? w2 : w3;
  const float4* s4 = (const float4*)src;
  int idx = blockIdx.x * 256 + threadIdx.x;
  float m = 0.f;
  for (int i = 0; i < 64; ++i) {
    float4 v = s4[idx + i * 16384];
    m = fmaxf(m, fmaxf(fmaxf(fabsf(v.x), fabsf(v.y)), fmaxf(fabsf(v.z), fabsf(v.w))));
  }
  for (int o = 32; o; o >>= 1) m = fmaxf(m, __shfl_down(m, o));
  __shared__ float red[4];
  if ((threadIdx.x & 63) == 0) red[threadIdx.x >> 6] = m;
  __syncthreads();
  if (threadIdx.x == 0) {
    m = fmaxf(fmaxf(red[0], red[1]), fmaxf(red[2], red[3]));
    atomicMax(&scal[blockIdx.y], __float_as_int(m));
  }
}

__global__ void k_quant(const float* __restrict__ x, const float* __restrict__ w1,
                        const float* __restrict__ w2, const float* __restrict__ w3,
                        u16* qx, u16* qw, const int* scal) {
  int a = blockIdx.y;
  const float* src = (a == 0) ? x : (a == 1) ? w1 : (a == 2) ? w2 : w3;
  u16* dst = (a == 0) ? qx : qw + (size_t)(a - 1) * TOKS * EMB;
  float mx = __int_as_float(scal[a]);
  float s = (a == 0) ? mx * 0.25f : mx / 3.0f;
  float lo = (a == 0) ? -4.f : -3.f;
  const float hi = 3.f;
  int idx = blockIdx.x * 256 + threadIdx.x;
  for (int i = 0; i < 16; ++i) {
    int j = idx + i * 65536;
    float4 v = ((const float4*)src)[j];
    ushort4 o;
    o.x = f2b(fminf(fmaxf(rintf(v.x / s), lo), hi));
    o.y = f2b(fminf(fmaxf(rintf(v.y / s), lo), hi));
    o.z = f2b(fminf(fmaxf(rintf(v.z / s), lo), hi));
    o.w = f2b(fminf(fmaxf(rintf(v.w / s), lo), hi));
    ((ushort4*)dst)[j] = o;
  }
}

// Fused QKV GEMM: C[t,o] = sum_c qx[t,c]*qw[o,c]*alpha + bias[o]  (z picks W/out)
__global__ __launch_bounds__(256) void k_gemm(const u16* __restrict__ qx, const u16* __restrict__ qw,
    const float* __restrict__ b1, const float* __restrict__ b2, const float* __restrict__ b3,
    const int* __restrict__ scal, u16* qo, u16* ko, u16* vo) {
  int z = blockIdx.z;
  const u16* W = qw + (size_t)z * TOKS * EMB;
  const float* bias = (z == 0) ? b1 : (z == 1) ? b2 : b3;
  u16* out = (z == 0) ? qo : (z == 1) ? ko : vo;
  float sx = __int_as_float(scal[0]) * 0.25f;
  float sw = __int_as_float(scal[1 + z]) / 3.0f;
  float alpha = sx * sw;
  float extra = (z == 0) ? RSQ : 1.0f;
  int t0 = blockIdx.y * 128, o0 = blockIdx.x * 128;
  __shared__ __align__(16) u16 As[128 * 32];
  __shared__ __align__(16) u16 Bs[128 * 32];
  int tid = threadIdx.x, lane = tid & 63, wid = tid >> 6;
  int mh = (wid >> 1) * 64, nh = (wid & 1) * 64;
  f32x4 acc[4][4] = {};
  const char* Ab = (const char*)qx;
  const char* Bb = (const char*)W;
  for (int kk = 0; kk < 64; ++kk) {
    for (int rr = 0; rr < 2; ++rr) {
      int off = rr * 4096 + tid * 16;
      int r = off >> 6, b = off & 63;
      char* lbase = (char*)As + rr * 4096 + wid * 1024;
      gload16(Ab + (size_t)(t0 + r) * 4096 + (size_t)kk * 64 + b, lbase);
      char* lbase2 = (char*)Bs + rr * 4096 + wid * 1024;
      gload16(Bb + (size_t)(o0 + r) * 4096 + (size_t)kk * 64 + b, lbase2);
    }
    __syncthreads();
    bf16x8 af[4], bfrag[4];
    for (int m = 0; m < 4; ++m)
      af[m] = *(const bf16x8*)(As + (mh + m * 16 + (lane & 15)) * 32 + (lane >> 4) * 8);
    for (int n = 0; n < 4; ++n)
      bfrag[n] = *(const bf16x8*)(Bs + (nh + n * 16 + (lane & 15)) * 32 + (lane >> 4) * 8);
    for (int m = 0; m < 4; ++m)
      for (int n = 0; n < 4; ++n)
        acc[m][n] = __builtin_amdgcn_mfma_f32_16x16x32_bf16(af[m], bfrag[n], acc[m][n], 0, 0, 0);
    __syncthreads();
  }
  for (int m = 0; m < 4; ++m)
    for (int n = 0; n < 4; ++n) {
      int ocol = o0 + nh + n * 16 + (lane & 15);
      int h = ocol >> 7, d = ocol & 127;
      float bb = bias[ocol];
      for (int r = 0; r < 4; ++r) {
        int trow = t0 + mh + m * 16 + (lane >> 4) * 4 + r;
        float v = (acc[m][n][r] * alpha + bb) * extra;
        out[(size_t)(h * TOKS + trow) * HS + d] = f2b(v);
      }
    }
}

__global__ void k_transpose(const u16* __restrict__ v, u16* vt) {
  int h = blockIdx.z, d0 = blockIdx.y * 64, t0 = blockIdx.x * 64;
  __shared__ u16 tile[64][65];
  int tid = threadIdx.x;
  for (int i = 0; i < 16; ++i) {
    int idx = i * 256 + tid, r = idx >> 6, c = idx & 63;
    tile[r][c] = v[(size_t)(h * TOKS + t0 + r) * HS + d0 + c];
  }
  __syncthreads();
  for (int i = 0; i < 16; ++i) {
    int idx = i * 256 + tid, r = idx >> 6, c = idx & 63;
    vt[(size_t)(h * HS + d0 + r) * TOKS + t0 + c] = tile[c][r];
  }
}

// denom: invden[q,k] = 1 / sum_h exp(att[h,q,k])
__global__ __launch_bounds__(512) void k_denom(const u16* __restrict__ q, const u16* __restrict__ k,
                                               float* invden) {
  int kt0 = blockIdx.x * 128, qt0 = blockIdx.y * 128;
  __shared__ __align__(16) u16 Ks[4 * 128 * 32]; // 32KB, [chunk][kp][32]
  int tid = threadIdx.x, lane = tid & 63, wid = tid >> 6;
  f32x4 den[8] = {};
  for (int h = 0; h < NH; ++h) {
    for (int rr = 0; rr < 4; ++rr) {
      int off = rr * 8192 + tid * 16;
      int c = off >> 13, r = (off >> 6) & 127, b = off & 63;
      gload16((const char*)k + (size_t)(h * TOKS + kt0 + r) * 256 + c * 64 + b,
              (char*)Ks + rr * 8192 + wid * 1024);
    }
    __syncthreads();
    f32x4 aacc[8] = {};
    for (int c = 0; c < 4; ++c) {
      bf16x8 aq = *(const bf16x8*)(q + (size_t)(h * TOKS + qt0 + wid * 16 + (lane & 15)) * 128
                                   + c * 32 + (lane >> 4) * 8);
      for (int n = 0; n < 8; ++n) {
        bf16x8 bk = *(const bf16x8*)(Ks + c * 128 * 32 + (n * 16 + (lane & 15)) * 32 + (lane >> 4) * 8);
        aacc[n] = __builtin_amdgcn_mfma_f32_16x16x32_bf16(aq, bk, aacc[n], 0, 0, 0);
      }
    }
    for (int n = 0; n < 8; ++n)
      for (int r = 0; r < 4; ++r) den[n][r] += __expf(aacc[n][r]);
    __syncthreads();
  }
  for (int n = 0; n < 8; ++n)
    for (int r = 0; r < 4; ++r) {
      int qrow = qt0 + wid * 16 + (lane >> 4) * 4 + r;
      int kcol = kt0 + n * 16 + (lane & 15);
      invden[(size_t)qrow * TOKS + kcol] = 1.0f / den[n][r];
    }
}

// attention: y[h,q,d] = sum_k exp(att)*invden[q,k] * v[h,k,d]
__global__ __launch_bounds__(512) void k_attn(const u16* __restrict__ q, const u16* __restrict__ k,
                                              const u16* __restrict__ vt, const float* __restrict__ invden,
                                              float* __restrict__ out) {
  int qt0 = blockIdx.x * 128, h = blockIdx.y;
  __shared__ __align__(16) u16 Ks[4 * 64 * 32];  // [chunk d][kp 64][32]
  __shared__ __align__(16) u16 Vt[2 * 128 * 32]; // [chunk kp][d 128][32]
  __shared__ __align__(16) u16 Ps[2 * 128 * 32]; // [chunk kp][q 128][32]
  int tid = threadIdx.x, lane = tid & 63, wid = tid >> 6;
  int qrb = qt0 + wid * 16;
  bf16x8 qf[4];
  for (int c = 0; c < 4; ++c)
    qf[c] = *(const bf16x8*)(q + (size_t)(h * TOKS + qrb + (lane & 15)) * 128 + c * 32 + (lane >> 4) * 8);
  f32x4 yacc[8] = {};
  for (int kb = 0; kb < 32; ++kb) {
    for (int rr = 0; rr < 2; ++rr) {
      int off = rr * 8192 + tid * 16;
      int b = off & 63;
      int kc = off >> 12, kr = (off >> 6) & 63;
      gload16((const char*)k + (size_t)(h * TOKS + kb * 64 + kr) * 256 + kc * 64 + b,
              (char*)Ks + rr * 8192 + wid * 1024);
      int vc = off >> 13, vr = (off >> 6) & 127;
      gload16((const char*)vt + (size_t)(h * HS + vr) * 4096 + kb * 128 + vc * 64 + b,
              (char*)Vt + rr * 8192 + wid * 1024);
    }
    __syncthreads();
    f32x4 pacc[4] = {};
    for (int c = 0; c < 4; ++c)
      for (int n = 0; n < 4; ++n) {
        bf16x8 bk = *(const bf16x8*)(Ks + c * 64 * 32 + (n * 16 + (lane & 15)) * 32 + (lane >> 4) * 8);
        pacc[n] = __builtin_amdgcn_mfma_f32_16x16x32_bf16(qf[c], bk, pacc[n], 0, 0, 0);
      }
    for (int n = 0; n < 4; ++n)
      for (int r = 0; r < 4; ++r) {
        int qr = wid * 16 + (lane >> 4) * 4 + r;
        int kcol = kb * 64 + n * 16 + (lane & 15);
        float e = __expf(pacc[n][r]) * invden[(size_t)(qt0 + qr) * TOKS + kcol];
        Ps[(n >> 1) * 128 * 32 + qr * 32 + (n & 1) * 16 + (lane & 15)] = f2b(e);
      }
    for (int ks = 0; ks < 2; ++ks) {
      bf16x8 pa = *(const bf16x8*)(Ps + ks * 128 * 32 + (wid * 16 + (lane & 15)) * 32 + (lane >> 4) * 8);
      for (int n = 0; n < 8; ++n) {
        bf16x8 bv = *(const bf16x8*)(Vt + ks * 128 * 32 + (n * 16 + (lane & 15)) * 32 + (lane >> 4) * 8);
        yacc[n] = __builtin_amdgcn_mfma_f32_16x16x32_bf16(pa, bv, yacc[n], 0, 0, 0);
      }
    }
    __syncthreads();
  }
  for (int n = 0; n < 8; ++n)
    for (int r = 0; r < 4; ++r) {
      int trow = qt0 + wid * 16 + (lane >> 4) * 4 + r;
      out[(size_t)(h * TOKS + trow) * HS + n * 16 + (lane & 15)] = yacc[n][r];
    }
}

extern "C" void kernel_launch(void* const* d_in, const int* in_sizes, int n_in,
                              void* d_out, int out_size, void* d_ws, size_t ws_size,
                              hipStream_t stream) {
  const float* x  = (const float*)d_in[0];
  const float* W1 = (const float*)d_in[1];
  const float* b1 = (const float*)d_in[2];
  const float* W2 = (const float*)d_in[3];
  const float* b2 = (const float*)d_in[4];
  const float* W3 = (const float*)d_in[5];
  const float* b3 = (const float*)d_in[6];
  char* ws = (char*)d_ws;
  int*   scal   = (int*)(ws + OFF_SCAL);
  u16*   qx     = (u16*)(ws + OFF_QX);
  u16*   qw     = (u16*)(ws + OFF_QW);
  u16*   qo     = (u16*)(ws + OFF_Q);
  u16*   ko     = (u16*)(ws + OFF_K);
  u16*   vo     = (u16*)(ws + OFF_V);
  u16*   vt     = (u16*)(ws + OFF_VT);
  float* invden = (float*)(ws + OFF_DEN);
  float* y      = (float*)d_out;

  hipLaunchKernelGGL(k_init, dim3(1), dim3(64), 0, stream, scal);
  hipLaunchKernelGGL(k_absmax, dim3(64, 4), dim3(256), 0, stream, x, W1, W2, W3, scal);
  hipLaunchKernelGGL(k_quant, dim3(256, 4), dim3(256), 0, stream, x, W1, W2, W3, qx, qw, scal);
  hipLaunchKernelGGL(k_gemm, dim3(16, 16, 3), dim3(256), 0, stream,
                     qx, qw, b1, b2, b3, scal, qo, ko, vo);
  hipLaunchKernelGGL(k_transpose, dim3(32, 2, 16), dim3(256), 0, stream, vo, vt);
  hipLaunchKernelGGL(k_denom, dim3(16, 16), dim3(512), 0, stream, qo, ko, invden);
  hipLaunchKernelGGL(k_attn, dim3(16, 16), dim3(512), 0, stream, qo, ko, vt, invden, y);
}